// Round 4
// baseline (344.453 us; speedup 1.0000x reference)
//
#include <hip/hip_runtime.h>
#include <hip/hip_bf16.h>

typedef __attribute__((ext_vector_type(8))) short bf16x8;
typedef __attribute__((ext_vector_type(4))) float f32x4;
typedef __attribute__((ext_vector_type(8))) unsigned short u16x8;

__device__ __forceinline__ unsigned short bf16_rne(float f) {
  union { float f; unsigned u; } c; c.f = f;
  unsigned u = c.u;
  return (unsigned short)((u + 0x7FFFu + ((u >> 16) & 1u)) >> 16);
}

// one v_cvt_pk_bf16_f32: low16 = bf16(lo), high16 = bf16(hi), RNE
__device__ __forceinline__ unsigned cvt_pk_bf16(float lo, float hi) {
  unsigned r;
  asm("v_cvt_pk_bf16_f32 %0, %1, %2" : "=v"(r) : "v"(lo), "v"(hi));
  return r;
}

// ---------------- prep: pack D (on-the-fly DCT-II basis), w1^T, w2^T into
// MFMA fragment-linear bf16 layout: [kstep][nfrag][lane][j], element =
// Beff[kstep*32 + (lane>>4)*8 + j][nfrag*16 + (lane&15)] ----------------
__global__ void fecam_prep(const float* __restrict__ w1, const float* __restrict__ w2,
                           unsigned short* __restrict__ Dp, unsigned short* __restrict__ w1p,
                           unsigned short* __restrict__ w2p) {
  int t = blockIdx.x * 256 + threadIdx.x;
  int lane = t & 63;
  int fr = t >> 6;
  int l16 = lane & 15, lh = lane >> 4;
  unsigned short o[8];
  if (fr < 512) {                            // D: K=512 (16 ksteps), N=512 (NF=32)
    int kstep = fr >> 5, nf = fr & 31;
    int n = nf * 16 + l16;
#pragma unroll
    for (int j = 0; j < 8; ++j) {
      int k = kstep * 32 + lh * 8 + j;
      int tt = (n * (2 * k + 1)) & 2047;     // exact angle reduction mod 2*pi
      float v = 2.0f * cosf((float)tt * 3.0679615757712823e-3f); // pi/1024
      o[j] = bf16_rne(v);
    }
    *(u16x8*)(Dp + (size_t)t * 8) = *(u16x8*)o;
  } else if (fr < 1536) {                    // w1^T: K=512 (16 ksteps), N=1024 (NF=64)
    int fr2 = fr - 512;
    int nf = fr2 & 63;
    int kstep = fr2 >> 6;
    int n = nf * 16 + l16;
#pragma unroll
    for (int j = 0; j < 8; ++j) {
      int k = kstep * 32 + lh * 8 + j;
      o[j] = bf16_rne(w1[(size_t)n * 512 + k]);
    }
    *(u16x8*)(w1p + ((size_t)fr2 * 64 + lane) * 8) = *(u16x8*)o;
  } else {                                   // w2^T: K=1024 (32 ksteps), N=512 (NF=32)
    int fr3 = fr - 1536;
    int nf = fr3 & 31;
    int kstep = fr3 >> 5;
    int n = nf * 16 + l16;
#pragma unroll
    for (int j = 0; j < 8; ++j) {
      int k = kstep * 32 + lh * 8 + j;
      o[j] = bf16_rne(w2[(size_t)n * 1024 + k]);
    }
    *(u16x8*)(w2p + ((size_t)fr3 * 64 + lane) * 8) = *(u16x8*)o;
  }
}

// ---------------- fused main: BM=64 rows, 1024 thr = 16 waves.
// GEMM1: wave = 64x32.  GEMM2: wave = 64x64 (full K, no chunking).
// h[64][1024] bf16 (128KB) overwrites sd after GEMM2.  GEMM3: wave = 64x32,
// full K=1024.  LDS 129KB -> 1 block/CU, 16 waves. ----------------
__global__ __launch_bounds__(1024, 4) void fecam_main(
    const float* __restrict__ x, const float* __restrict__ gamma, const float* __restrict__ beta,
    const unsigned short* __restrict__ Dp, const unsigned short* __restrict__ w1p,
    const unsigned short* __restrict__ w2p, float* __restrict__ out) {
  extern __shared__ char smem[];
  // [0,65536):      x bf16 [64][512] swz, then sd in place, then h rows part
  // [65536,131072): h upper part (h = [64][1024] bf16 from smem+0, stride 2048)
  float* rs1 = (float*)(smem + 131072);   // [64] LN1 sums
  float* rq1 = rs1 + 64;
  float* rs2 = rq1 + 64;
  float* rq2 = rs2 + 64;

  const int tid = threadIdx.x;
  const int lane = tid & 63;
  const int w = tid >> 6;            // wave 0..15
  const int l16 = lane & 15, lh = lane >> 4;
  const int b = blockIdx.x >> 3;
  const int c0 = (blockIdx.x & 7) * 64;
  const int n0 = w * 32;             // wave's 32-col strip (GEMM1 / GEMM3 / epilogue)

  if (tid < 256) rs1[tid] = 0.0f;    // zero all 4 stat arrays

  // ---- phase 0: stage x rows -> smem[0..64KB) bf16, [64][512] swz ----
  {
    const int cc = lane;             // row (c offset)
    const int kg = w;                // k-pair group 0..15
    const float* xb = x + ((size_t)b * 512) * 512 + c0 + cc;
#pragma unroll
    for (int kb = 0; kb < 16; ++kb) {
      int k = kb * 32 + kg * 2;
      float v0 = xb[(size_t)k * 512];
      float v1 = xb[(size_t)(k + 1) * 512];
      unsigned pk = cvt_pk_bf16(v0, v1);
      int byte = (cc * 1024 + k * 2) ^ ((cc & 7) << 4);
      *(unsigned*)(smem + byte) = pk;
    }
  }

  float g_[2], b_[2];
#pragma unroll
  for (int jj = 0; jj < 2; ++jj) {
    g_[jj] = gamma[n0 + jj * 16 + l16];
    b_[jj] = beta[n0 + jj * 16 + l16];
  }

  __syncthreads();

  // ======== GEMM1 + LN1 + sd (scoped so acc1 dies) ========
  {
    f32x4 acc1[4][2];
#pragma unroll
    for (int i = 0; i < 4; ++i)
#pragma unroll
      for (int jj = 0; jj < 2; ++jj) acc1[i][jj] = (f32x4){0.f, 0.f, 0.f, 0.f};

#pragma unroll 2
    for (int kstep = 0; kstep < 16; ++kstep) {
      bf16x8 af[4];
#pragma unroll
      for (int i = 0; i < 4; ++i) {
        int r = i * 16 + l16;
        int byte = (r * 1024 + kstep * 64 + lh * 16) ^ ((r & 7) << 4);
        af[i] = *(const bf16x8*)(smem + byte);
      }
#pragma unroll
      for (int jj = 0; jj < 2; ++jj) {
        bf16x8 bf = *(const bf16x8*)(Dp + (((size_t)kstep * 32 + (w * 2 + jj)) * 64 + lane) * 8);
#pragma unroll
        for (int i = 0; i < 4; ++i)
          acc1[i][jj] = __builtin_amdgcn_mfma_f32_16x16x32_bf16(af[i], bf, acc1[i][jj], 0, 0, 0);
      }
    }

    // LN1 stats over this wave's 32 cols -> LDS atomics
#pragma unroll
    for (int i = 0; i < 4; ++i) {
#pragma unroll
      for (int q = 0; q < 4; ++q) {
        float s = acc1[i][0][q] + acc1[i][1][q];
        float ss = acc1[i][0][q] * acc1[i][0][q] + acc1[i][1][q] * acc1[i][1][q];
#pragma unroll
        for (int m = 1; m <= 8; m <<= 1) {
          s += __shfl_xor(s, m);
          ss += __shfl_xor(ss, m);
        }
        if (l16 == 0) {
          atomicAdd(&rs1[i * 16 + lh * 4 + q], s);
          atomicAdd(&rq1[i * 16 + lh * 4 + q], ss);
        }
      }
    }
    __syncthreads();   // GEMM1 x-reads done; stats complete

    // normalize -> sd bf16 into smem[0..64KB) (overwrites x), paired rows q/q+1
#pragma unroll
    for (int i = 0; i < 4; ++i) {
      float mu_[4], rstd_[4];
#pragma unroll
      for (int q = 0; q < 4; ++q) {
        int r = i * 16 + lh * 4 + q;
        float mu = rs1[r] * (1.0f / 512.0f);
        float var = rq1[r] * (1.0f / 512.0f) - mu * mu;
        mu_[q] = mu;
        rstd_[q] = rsqrtf(var + 1e-6f);
      }
#pragma unroll
      for (int jj = 0; jj < 2; ++jj) {
        int col = n0 + jj * 16 + l16;
#pragma unroll
        for (int q = 0; q < 4; q += 2) {
          int r0 = i * 16 + lh * 4 + q;
          float v0 = (acc1[i][jj][q] - mu_[q]) * rstd_[q] * g_[jj] + b_[jj];
          float v1 = (acc1[i][jj][q + 1] - mu_[q + 1]) * rstd_[q + 1] * g_[jj] + b_[jj];
          unsigned pk = cvt_pk_bf16(v0, v1);
          int byte0 = (r0 * 1024 + col * 2) ^ ((r0 & 7) << 4);
          int byte1 = ((r0 + 1) * 1024 + col * 2) ^ (((r0 + 1) & 7) << 4);
          *(unsigned short*)(smem + byte0) = (unsigned short)pk;
          *(unsigned short*)(smem + byte1) = (unsigned short)(pk >> 16);
        }
      }
    }
  }
  __syncthreads();

  // ======== GEMM2: h = relu(sd @ w1^T), wave = 64 rows x 64 cols, full K ========
  {
    f32x4 acc2[4][4];
#pragma unroll
    for (int i = 0; i < 4; ++i)
#pragma unroll
      for (int jn = 0; jn < 4; ++jn) acc2[i][jn] = (f32x4){0.f, 0.f, 0.f, 0.f};

#pragma unroll 2
    for (int kstep = 0; kstep < 16; ++kstep) {
      bf16x8 af[4];
#pragma unroll
      for (int i = 0; i < 4; ++i) {
        int r = i * 16 + l16;
        int byte = (r * 1024 + kstep * 64 + lh * 16) ^ ((r & 7) << 4);
        af[i] = *(const bf16x8*)(smem + byte);
      }
#pragma unroll
      for (int jn = 0; jn < 4; ++jn) {
        bf16x8 bf = *(const bf16x8*)(
            w1p + (((size_t)kstep * 64 + (w * 4 + jn)) * 64 + lane) * 8);
#pragma unroll
        for (int i = 0; i < 4; ++i)
          acc2[i][jn] = __builtin_amdgcn_mfma_f32_16x16x32_bf16(af[i], bf, acc2[i][jn], 0, 0, 0);
      }
    }
    __syncthreads();   // everyone's sd reads done; smem now reusable for h

    // relu -> h bf16 [64][1024] (stride 2048B) from smem+0, paired rows
#pragma unroll
    for (int i = 0; i < 4; ++i) {
#pragma unroll
      for (int jn = 0; jn < 4; ++jn) {
        int col = w * 64 + jn * 16 + l16;
#pragma unroll
        for (int q = 0; q < 4; q += 2) {
          int r0 = i * 16 + lh * 4 + q;
          float v0 = fmaxf(acc2[i][jn][q], 0.0f);
          float v1 = fmaxf(acc2[i][jn][q + 1], 0.0f);
          unsigned pk = cvt_pk_bf16(v0, v1);
          int byte0 = (r0 * 2048 + col * 2) ^ ((r0 & 7) << 4);
          int byte1 = ((r0 + 1) * 2048 + col * 2) ^ (((r0 + 1) & 7) << 4);
          *(unsigned short*)(smem + byte0) = (unsigned short)pk;
          *(unsigned short*)(smem + byte1) = (unsigned short)(pk >> 16);
        }
      }
    }
  }
  __syncthreads();

  // ======== GEMM3: fw = h @ w2^T, wave = 64 rows x 32 cols, K=1024 ========
  f32x4 acc3[4][2];
#pragma unroll
  for (int i = 0; i < 4; ++i)
#pragma unroll
    for (int jj = 0; jj < 2; ++jj) acc3[i][jj] = (f32x4){0.f, 0.f, 0.f, 0.f};

#pragma unroll 2
  for (int kstep = 0; kstep < 32; ++kstep) {
    bf16x8 af[4];
#pragma unroll
    for (int i = 0; i < 4; ++i) {
      int r = i * 16 + l16;
      int byte = (r * 2048 + kstep * 64 + lh * 16) ^ ((r & 7) << 4);
      af[i] = *(const bf16x8*)(smem + byte);
    }
#pragma unroll
    for (int jj = 0; jj < 2; ++jj) {
      bf16x8 bf = *(const bf16x8*)(
          w2p + (((size_t)kstep * 32 + (w * 2 + jj)) * 64 + lane) * 8);
#pragma unroll
      for (int i = 0; i < 4; ++i)
        acc3[i][jj] = __builtin_amdgcn_mfma_f32_16x16x32_bf16(af[i], bf, acc3[i][jj], 0, 0, 0);
    }
  }

  // ---- sigmoid ----
#pragma unroll
  for (int i = 0; i < 4; ++i)
#pragma unroll
    for (int jj = 0; jj < 2; ++jj)
#pragma unroll
      for (int q = 0; q < 4; ++q)
        acc3[i][jj][q] = 1.0f / (1.0f + __expf(-acc3[i][jj][q]));

  // ---- LN2 stats ----
#pragma unroll
  for (int i = 0; i < 4; ++i) {
#pragma unroll
    for (int q = 0; q < 4; ++q) {
      float s = acc3[i][0][q] + acc3[i][1][q];
      float ss = acc3[i][0][q] * acc3[i][0][q] + acc3[i][1][q] * acc3[i][1][q];
#pragma unroll
      for (int m = 1; m <= 8; m <<= 1) {
        s += __shfl_xor(s, m);
        ss += __shfl_xor(ss, m);
      }
      if (l16 == 0) {
        atomicAdd(&rs2[i * 16 + lh * 4 + q], s);
        atomicAdd(&rq2[i * 16 + lh * 4 + q], ss);
      }
    }
  }
  __syncthreads();

  // ---- LN2 normalize, multiply by xp, store out[b][col][c0+r] ----
#pragma unroll
  for (int i = 0; i < 4; ++i) {
    float mu_[4], rstd_[4];
#pragma unroll
    for (int q = 0; q < 4; ++q) {
      int r = i * 16 + lh * 4 + q;
      float mu = rs2[r] * (1.0f / 512.0f);
      float var = rq2[r] * (1.0f / 512.0f) - mu * mu;
      mu_[q] = mu;
      rstd_[q] = rsqrtf(var + 1e-6f);
    }
#pragma unroll
    for (int jj = 0; jj < 2; ++jj) {
      int col = n0 + jj * 16 + l16;
      size_t base = ((size_t)b * 512 + col) * 512 + c0 + i * 16 + lh * 4;
      float4 xv = *(const float4*)(x + base);
      float4 ov;
#pragma unroll
      for (int q = 0; q < 4; ++q) {
        float fn = (acc3[i][jj][q] - mu_[q]) * rstd_[q] * g_[jj] + b_[jj];
        (&ov.x)[q] = (&xv.x)[q] * fn;
      }
      *(float4*)(out + base) = ov;
    }
  }
}

extern "C" void kernel_launch(void* const* d_in, const int* in_sizes, int n_in,
                              void* d_out, int out_size, void* d_ws, size_t ws_size,
                              hipStream_t stream) {
  const float* x = (const float*)d_in[0];
  const float* gamma = (const float*)d_in[1];
  const float* beta = (const float*)d_in[2];
  const float* w1 = (const float*)d_in[3];
  const float* w2 = (const float*)d_in[4];

  unsigned short* Dp = (unsigned short*)d_ws;        // 16*32*64*8  = 262144 bf16
  unsigned short* w1p = Dp + 262144;                 // 16*64*64*8  = 524288 bf16
  unsigned short* w2p = w1p + 524288;                // 32*32*64*8  = 524288 bf16

  fecam_prep<<<640, 256, 0, stream>>>(w1, w2, Dp, w1p, w2p);
  fecam_main<<<1024, 1024, 132096, stream>>>(x, gamma, beta, Dp, w1p, w2p, (float*)d_out);
}